// Round 3
// baseline (497.368 us; speedup 1.0000x reference)
//
#include <hip/hip_runtime.h>
#include <math.h>

// NeighborlistVerletNsq: N=4096 particles, P = N(N-1)/2 pairs.
// Outputs (flattened float32, in return order):
//   [0   , 4P ) pairs  [2,2P]: row0 = concat(i,j), row1 = concat(j,i)
//   [4P  , 6P ) d_full [2P,1]: concat(d_m, d_m)
//   [6P  , 12P) r_full [2P,3]: concat(r_m, -r_m), row-major
//   [12P , 14P) mask   [2P]  : concat(mask, mask) as 0/1
//
// R8 == R7 resubmitted (R7 bench died on container acquisition, not kernel).
// Discriminate "14-stream store pattern limits write BW" (H-A) vs "kernel
// already at write roofline, dur dominated by harness poison fills" (H-B).
// Grid is (chunk, group): each block writes ONLY its group's output streams
// for one contiguous 1024-pair chunk:
//   group 0 -> pairs rows (4 streams, index-only math, no pos loads)
//   group 1 -> d_full     (2 streams, full pair math)
//   group 2 -> r_full     (2 regions of contiguous 12B triplets)
//   group 3 -> mask       (2 streams)
// Streams/block drops 14 -> 2..6; pair math recomputed by groups 1-3 (VALU
// cost is negligible vs stores). float4 stores kept from R6. Scalar tail
// fallback per group; index-load fallback kernel if P != N(N-1)/2.
//
// Numerics (exact numpy match, verified absmax 0.0 through R6 — unchanged):
//   remainder(t,L) for t in (-L,2L):  t>=L -> t-L (Sterbenz-exact == fmod);
//   t<0 -> t+L (same single rounding as numpy's fixup); else t.
//   norm: no-fma ((x*x + y*y) + z*z), IEEE sqrtf.  Mask uses d<=0.5 on the
//   ROUNDED d (not d2<=0.25 — they differ at the ulp boundary).

#define CUTOFF_F 0.5f
#define BLOCK 256
#define PPT 4
#define CHUNK (BLOCK * PPT)

__device__ __forceinline__ float pbc_wrap_fast(float r, float L, float h) {
    float t = __fadd_rn(r, h);
    float m = (t >= L) ? __fsub_rn(t, L)
            : (t < 0.0f ? __fadd_rn(t, L) : t);
    return __fsub_rn(m, h);
}

__device__ __forceinline__ void compute_pair_pp(float pix, float piy, float piz,
                                                float pjx, float pjy, float pjz,
                                                float Lx, float Ly, float Lz,
                                                float hx, float hy, float hz,
                                                float& dm,
                                                float& mx, float& my, float& mz,
                                                float& mk) {
    float rx = __fsub_rn(pix, pjx);
    float ry = __fsub_rn(piy, pjy);
    float rz = __fsub_rn(piz, pjz);

    rx = pbc_wrap_fast(rx, Lx, hx);
    ry = pbc_wrap_fast(ry, Ly, hy);
    rz = pbc_wrap_fast(rz, Lz, hz);

    float d2 = __fadd_rn(__fadd_rn(__fmul_rn(rx, rx), __fmul_rn(ry, ry)),
                         __fmul_rn(rz, rz));
    float d = sqrtf(d2);

    const bool keep = (d <= CUTOFF_F);
    dm = keep ? d  : 0.0f;
    mx = keep ? rx : 0.0f;
    my = keep ? ry : 0.0f;
    mz = keep ? rz : 0.0f;
    mk = keep ? 1.0f : 0.0f;
}

__device__ __forceinline__ void write_pair(float* __restrict__ out, long long P,
                                           long long p, float fi, float fj,
                                           float dm, float mx, float my,
                                           float mz, float mk) {
    out[p]          = fi;
    out[P + p]      = fj;
    out[2 * P + p]  = fj;
    out[3 * P + p]  = fi;
    out[4 * P + p]  = dm;
    out[5 * P + p]  = dm;
    long long b0 = 6 * P + 3 * p;
    out[b0 + 0] = mx;  out[b0 + 1] = my;  out[b0 + 2] = mz;
    long long b1 = 6 * P + 3 * (P + p);
    out[b1 + 0] = -mx; out[b1 + 1] = -my; out[b1 + 2] = -mz;
    out[12 * P + p] = mk;
    out[13 * P + p] = mk;
}

// offset of first pair in row i: f(i) = i*(2N-1-i)/2
__device__ __forceinline__ long long row_off(long long i, long long N) {
    return (long long)(((unsigned long long)i *
                        (unsigned long long)(2 * N - 1 - i)) >> 1);
}

// invert triu_indices at p0 -> (i, j)
__device__ __forceinline__ void invert_triu(long long p0, int N,
                                            int& oi, int& oj) {
    const double twoNm1 = (double)(2 * N - 1);
    const double D = twoNm1 * twoNm1 - 8.0 * (double)p0;
    long long i64 = (long long)((twoNm1 - sqrt(D)) * 0.5);
    if (i64 < 0) i64 = 0;
    if (i64 > N - 2) i64 = N - 2;
    while (row_off(i64 + 1, N) <= p0) ++i64;
    while (row_off(i64, N) > p0) --i64;
    oi = (int)i64;
    oj = (int)(p0 - row_off(i64, N) + i64 + 1);
}

// grid: (num_chunk_blocks, 4). blockIdx.y selects the output-stream group.
__global__ __launch_bounds__(BLOCK)
void nl_nsq_split(const float* __restrict__ pos,
                  const float* __restrict__ box,
                  float*       __restrict__ out,
                  long long P, int N) {
    const long long t  = (long long)blockIdx.x * BLOCK + threadIdx.x;
    const long long p0 = t * PPT;
    if (p0 >= P) return;
    const unsigned grp = blockIdx.y;   // wave-uniform

    int i, j;
    invert_triu(p0, N, i, j);

    const int nPairs = (int)((P - p0 < (long long)PPT) ? (P - p0)
                                                       : (long long)PPT);
    const bool vec_ok = (nPairs == PPT) && ((P & 3LL) == 0LL);

    if (grp == 0u) {
        // pairs rows: indices only, no position loads, no mask
        float fi[PPT], fj[PPT];
        int ii = i, jj = j;
#pragma unroll
        for (int q = 0; q < PPT; ++q) {
            if (q < nPairs) {
                fi[q] = (float)ii;
                fj[q] = (float)jj;
                if (++jj >= N) { ++ii; jj = ii + 1; }
            } else {
                fi[q] = fj[q] = 0.0f;
            }
        }
        if (vec_ok) {
            *reinterpret_cast<float4*>(out + p0)
                = make_float4(fi[0], fi[1], fi[2], fi[3]);
            *reinterpret_cast<float4*>(out + P + p0)
                = make_float4(fj[0], fj[1], fj[2], fj[3]);
            *reinterpret_cast<float4*>(out + 2 * P + p0)
                = make_float4(fj[0], fj[1], fj[2], fj[3]);
            *reinterpret_cast<float4*>(out + 3 * P + p0)
                = make_float4(fi[0], fi[1], fi[2], fi[3]);
        } else {
            for (int q = 0; q < nPairs; ++q) {
                long long p = p0 + q;
                out[p]         = fi[q];
                out[P + p]     = fj[q];
                out[2 * P + p] = fj[q];
                out[3 * P + p] = fi[q];
            }
        }
        return;
    }

    // groups 1-3: full pair math for the chunk
    const float Lx = box[0], Ly = box[4], Lz = box[8];
    const float hx = Lx * 0.5f, hy = Ly * 0.5f, hz = Lz * 0.5f;

    float pix = pos[3 * i + 0], piy = pos[3 * i + 1], piz = pos[3 * i + 2];

    float dm[PPT], mx[PPT], my[PPT], mz[PPT], mk[PPT];
#pragma unroll
    for (int q = 0; q < PPT; ++q) {
        if (q < nPairs) {
            float pjx = pos[3 * j + 0];
            float pjy = pos[3 * j + 1];
            float pjz = pos[3 * j + 2];
            compute_pair_pp(pix, piy, piz, pjx, pjy, pjz,
                            Lx, Ly, Lz, hx, hy, hz,
                            dm[q], mx[q], my[q], mz[q], mk[q]);
            if (q + 1 < nPairs) {
                if (++j >= N) {
                    ++i; j = i + 1;   // row crossing (rare)
                    pix = pos[3 * i + 0];
                    piy = pos[3 * i + 1];
                    piz = pos[3 * i + 2];
                }
            }
        } else {
            dm[q] = mx[q] = my[q] = mz[q] = mk[q] = 0.0f;
        }
    }

    if (grp == 1u) {                      // d_full: 2 streams
        if (vec_ok) {
            float4 v = make_float4(dm[0], dm[1], dm[2], dm[3]);
            *reinterpret_cast<float4*>(out + 4 * P + p0) = v;
            *reinterpret_cast<float4*>(out + 5 * P + p0) = v;
        } else {
            for (int q = 0; q < nPairs; ++q) {
                out[4 * P + p0 + q] = dm[q];
                out[5 * P + p0 + q] = dm[q];
            }
        }
    } else if (grp == 2u) {               // r_full: 2 triplet regions
        if (vec_ok) {
            const long long b0 = 6 * P + 3 * p0;
            *reinterpret_cast<float4*>(out + b0 + 0)
                = make_float4(mx[0], my[0], mz[0], mx[1]);
            *reinterpret_cast<float4*>(out + b0 + 4)
                = make_float4(my[1], mz[1], mx[2], my[2]);
            *reinterpret_cast<float4*>(out + b0 + 8)
                = make_float4(mz[2], mx[3], my[3], mz[3]);
            const long long b1 = 6 * P + 3 * (P + p0);
            *reinterpret_cast<float4*>(out + b1 + 0)
                = make_float4(-mx[0], -my[0], -mz[0], -mx[1]);
            *reinterpret_cast<float4*>(out + b1 + 4)
                = make_float4(-my[1], -mz[1], -mx[2], -my[2]);
            *reinterpret_cast<float4*>(out + b1 + 8)
                = make_float4(-mz[2], -mx[3], -my[3], -mz[3]);
        } else {
            for (int q = 0; q < nPairs; ++q) {
                long long p = p0 + q;
                long long b0 = 6 * P + 3 * p;
                out[b0 + 0] = mx[q]; out[b0 + 1] = my[q]; out[b0 + 2] = mz[q];
                long long b1 = 6 * P + 3 * (P + p);
                out[b1 + 0] = -mx[q]; out[b1 + 1] = -my[q]; out[b1 + 2] = -mz[q];
            }
        }
    } else {                              // mask: 2 streams
        if (vec_ok) {
            float4 v = make_float4(mk[0], mk[1], mk[2], mk[3]);
            *reinterpret_cast<float4*>(out + 12 * P + p0) = v;
            *reinterpret_cast<float4*>(out + 13 * P + p0) = v;
        } else {
            for (int q = 0; q < nPairs; ++q) {
                out[12 * P + p0 + q] = mk[q];
                out[13 * P + p0 + q] = mk[q];
            }
        }
    }
}

__global__ __launch_bounds__(BLOCK)
void nl_nsq_loadidx(const float* __restrict__ pos,
                    const float* __restrict__ box,
                    const int*   __restrict__ ip,
                    const int*   __restrict__ jp,
                    float*       __restrict__ out,
                    long long P) {
    const long long p = (long long)blockIdx.x * BLOCK + threadIdx.x;
    if (p >= P) return;

    const int i = ip[p];
    const int j = jp[p];

    const float Lx = box[0], Ly = box[4], Lz = box[8];
    const float hx = Lx * 0.5f, hy = Ly * 0.5f, hz = Lz * 0.5f;

    float dm, mx, my, mz, mk;
    compute_pair_pp(pos[3 * i + 0], pos[3 * i + 1], pos[3 * i + 2],
                    pos[3 * j + 0], pos[3 * j + 1], pos[3 * j + 2],
                    Lx, Ly, Lz, hx, hy, hz, dm, mx, my, mz, mk);
    write_pair(out, P, p, (float)i, (float)j, dm, mx, my, mz, mk);
}

extern "C" void kernel_launch(void* const* d_in, const int* in_sizes, int n_in,
                              void* d_out, int out_size, void* d_ws, size_t ws_size,
                              hipStream_t stream) {
    const float* pos = (const float*)d_in[0];  // [N,3]
    const float* box = (const float*)d_in[1];  // [3,3]
    const int*   ip  = (const int*)d_in[2];    // [P]
    const int*   jp  = (const int*)d_in[3];    // [P]
    float*       out = (float*)d_out;

    const long long P = (long long)in_sizes[2];
    const int       N = in_sizes[0] / 3;

    if (P == (long long)N * (N - 1) / 2) {
        const long long nb = (P + CHUNK - 1) / CHUNK;   // chunk blocks
        dim3 grid((unsigned)nb, 4, 1);
        nl_nsq_split<<<grid, BLOCK, 0, stream>>>(pos, box, out, P, N);
    } else {
        const long long grid = (P + BLOCK - 1) / BLOCK;
        nl_nsq_loadidx<<<(dim3)(unsigned)grid, BLOCK, 0, stream>>>(
            pos, box, ip, jp, out, P);
    }
}